// Round 3
// baseline (221.705 us; speedup 1.0000x reference)
//
#include <hip/hip_runtime.h>
#include <hip/hip_bf16.h>

// Problem constants (fixed by the reference).
#define BSZ 4
#define SEQ 512
#define DMODEL 512
#define NHEAD 8
#define DKH 64
#define EPSLN 1e-6f

typedef short bf16x8 __attribute__((ext_vector_type(8)));
typedef float f32x4 __attribute__((ext_vector_type(4)));

// fp32 -> bf16 round-to-nearest-even
static __device__ __forceinline__ short f2bf(float x) {
  unsigned u = __builtin_bit_cast(unsigned, x);
  u = (u + 0x7FFFu + ((u >> 16) & 1u)) >> 16;
  return (short)u;
}
static __device__ __forceinline__ bf16x8 cvt8(float4 a, float4 b) {
  bf16x8 r;
  r[0] = f2bf(a.x); r[1] = f2bf(a.y); r[2] = f2bf(a.z); r[3] = f2bf(a.w);
  r[4] = f2bf(b.x); r[5] = f2bf(b.y); r[6] = f2bf(b.z); r[7] = f2bf(b.w);
  return r;
}
static __device__ __forceinline__ unsigned pk2(float a, float b) {
  return (unsigned)(unsigned short)f2bf(a) |
         ((unsigned)(unsigned short)f2bf(b) << 16);
}
// async 16B/lane global -> LDS (lds dest = wave-uniform base + lane*16)
static __device__ __forceinline__ void async_cp16(const void* g, void* l) {
  __builtin_amdgcn_global_load_lds(
      (const __attribute__((address_space(1))) unsigned int*)g,
      (__attribute__((address_space(3))) unsigned int*)l, 16, 0, 0);
}

// ---------------------------------------------------------------------------
// Cast q,k,v (fp32) -> bf16, removing in-GEMM VALU conversion cost.
// ---------------------------------------------------------------------------
__global__ __launch_bounds__(256) void cast3_kernel(
    const float* __restrict__ q, const float* __restrict__ k,
    const float* __restrict__ v, short* __restrict__ qb,
    short* __restrict__ kb, short* __restrict__ vb) {
  const float* s; short* d;
  switch (blockIdx.y) {
    case 0: s = q; d = qb; break;
    case 1: s = k; d = kb; break;
    default: s = v; d = vb; break;
  }
  const size_t idx = (size_t)blockIdx.x * 2048 + (size_t)threadIdx.x * 8;
  float4 a = *(const float4*)&s[idx];
  float4 b = *(const float4*)&s[idx + 4];
  *(bf16x8*)&d[idx] = cvt8(a, b);
}

// ---------------------------------------------------------------------------
// W (fp32, [K][N]) -> W^T (bf16, [N][K]): B-fragments become k-contiguous.
// ---------------------------------------------------------------------------
__global__ __launch_bounds__(256) void wcast_kernel(
    const float* __restrict__ Wq, const float* __restrict__ Wk,
    const float* __restrict__ Wv, const float* __restrict__ Wo,
    short* __restrict__ Wqt, short* __restrict__ Wkt,
    short* __restrict__ Wvt, short* __restrict__ Wot) {
  __shared__ float T[64][65];
  const float* src; short* dst;
  switch (blockIdx.z) {
    case 0: src = Wq; dst = Wqt; break;
    case 1: src = Wk; dst = Wkt; break;
    case 2: src = Wv; dst = Wvt; break;
    default: src = Wo; dst = Wot; break;
  }
  const int k0 = blockIdx.x * 64, n0 = blockIdx.y * 64;
  const int tid = threadIdx.x;
  const int n4 = (tid & 15) * 4, kk = tid >> 4;
#pragma unroll
  for (int p = 0; p < 4; ++p) {
    float4 v = *(const float4*)&src[(size_t)(k0 + kk + p * 16) * DMODEL + n0 + n4];
    T[kk + p * 16][n4 + 0] = v.x;
    T[kk + p * 16][n4 + 1] = v.y;
    T[kk + p * 16][n4 + 2] = v.z;
    T[kk + p * 16][n4 + 3] = v.w;
  }
  __syncthreads();
  const int k4 = (tid & 15) * 4;
#pragma unroll
  for (int p = 0; p < 4; ++p) {
    const int nn = (tid >> 4) + p * 16;
    float x0 = T[k4 + 0][nn], x1 = T[k4 + 1][nn];
    float x2 = T[k4 + 2][nn], x3 = T[k4 + 3][nn];
    uint2 u; u.x = pk2(x0, x1); u.y = pk2(x2, x3);
    *(uint2*)&dst[(size_t)(n0 + nn) * DMODEL + k0 + k4] = u;
  }
}

// ---------------------------------------------------------------------------
// m97-style GEMM body: C[128x128] = A(bf16 [M][512]) @ Wt(bf16 [N][512])^T
// + bias. 256 thr / 4 waves (64x64 each, 4x4 MFMA tiles). global_load_lds
// staging, rotating double-buffer, ONE barrier per k-step: stage(k+1) is
// issued AFTER the barrier so its latency overlaps compute(k).
// omode: 0 fp32 row-major; 1 bf16 row-major; 2 bf16 Vt[c][h][d][j] scatter.
// ---------------------------------------------------------------------------
__device__ __forceinline__ void gemm_body(
    const short* __restrict__ A, const short* __restrict__ Wt,
    const float* __restrict__ bias, void* __restrict__ out, int omode) {
  __shared__ short As[2][128 * 32];
  __shared__ short Bs[2][128 * 32];
  const int tid = threadIdx.x;
  const int w = tid >> 6, lane = tid & 63;
  const int l15 = lane & 15, q = lane >> 4;
  const int wm = w >> 1, wn = w & 1;
  const int bn = blockIdx.x * 128, bm = blockIdx.y * 128;
  const int wu = __builtin_amdgcn_readfirstlane(w);
  const int srow = wu * 16 + (lane >> 2);  // staging row (issue 0)
  const int sch = lane & 3;                // 16B chunk within 64B row

  f32x4 acc[4][4] = {};  // [mt][nt]

  // --- staging: 8KB A-tile (128r x 32k) + 8KB B-tile, 2 issues each ---
#define GSTAGE(k0, buf)                                                      \
  {                                                                          \
    const short* ga0 = A + (size_t)(bm + srow) * 512 + (k0) + sch * 8;       \
    const short* ga1 = A + (size_t)(bm + srow + 64) * 512 + (k0) + sch * 8;  \
    const short* gb0 = Wt + (size_t)(bn + srow) * 512 + (k0) + sch * 8;      \
    const short* gb1 = Wt + (size_t)(bn + srow + 64) * 512 + (k0) + sch * 8; \
    async_cp16(ga0, &As[buf][wu * 512]);                                     \
    async_cp16(ga1, &As[buf][(4 + wu) * 512]);                               \
    async_cp16(gb0, &Bs[buf][wu * 512]);                                     \
    async_cp16(gb1, &Bs[buf][(4 + wu) * 512]);                               \
  }

  GSTAGE(0, 0);
  for (int ks = 0; ks < 16; ++ks) {
    __syncthreads();                       // drains stage(ks) (vmcnt0)
    if (ks < 15) GSTAGE((ks + 1) * 32, (ks + 1) & 1);
    const short* a = As[ks & 1];
    const short* bsh = Bs[ks & 1];
    bf16x8 af[4], bfr[4];
#pragma unroll
    for (int mt = 0; mt < 4; ++mt)
      af[mt] = *(const bf16x8*)&a[(wm * 64 + mt * 16 + l15) * 32 + q * 8];
#pragma unroll
    for (int nt = 0; nt < 4; ++nt)
      bfr[nt] = *(const bf16x8*)&bsh[(wn * 64 + nt * 16 + l15) * 32 + q * 8];
#pragma unroll
    for (int mt = 0; mt < 4; ++mt)
#pragma unroll
      for (int nt = 0; nt < 4; ++nt)
        acc[mt][nt] = __builtin_amdgcn_mfma_f32_16x16x32_bf16(
            af[mt], bfr[nt], acc[mt][nt], 0, 0, 0);
  }
#undef GSTAGE

  float bv[4];
#pragma unroll
  for (int nt = 0; nt < 4; ++nt) bv[nt] = bias[bn + wn * 64 + nt * 16 + l15];
#pragma unroll
  for (int mt = 0; mt < 4; ++mt)
#pragma unroll
    for (int nt = 0; nt < 4; ++nt) {
      const int col = bn + wn * 64 + nt * 16 + l15;
#pragma unroll
      for (int r = 0; r < 4; ++r) {
        const int row = bm + wm * 64 + mt * 16 + q * 4 + r;
        const float val = acc[mt][nt][r] + bv[nt];
        if (omode == 0) {
          ((float*)out)[(size_t)row * 512 + col] = val;
        } else if (omode == 1) {
          ((short*)out)[(size_t)row * 512 + col] = f2bf(val);
        } else {
          const int cc = row >> 9, j = row & 511;
          const int hh = col >> 6, d = col & 63;
          ((short*)out)[(((size_t)(cc * 8 + hh) * 64 + d) << 9) + j] = f2bf(val);
        }
      }
    }
}

__global__ __launch_bounds__(256, 2) void proj_gemm(
    const short* qb, const short* kb, const short* vb,
    const short* Wqt, const short* Wkt, const short* Wvt,
    const float* bq, const float* bk, const float* bvs,
    float* Qp, short* Kb, short* Vt) {
  const short* A; const short* Wt; const float* bias; void* out; int omode;
  switch (blockIdx.z) {
    case 0: A = qb; Wt = Wqt; bias = bq; out = Qp; omode = 0; break;
    case 1: A = kb; Wt = Wkt; bias = bk; out = Kb; omode = 1; break;
    default: A = vb; Wt = Wvt; bias = bvs; out = Vt; omode = 2; break;
  }
  gemm_body(A, Wt, bias, out, omode);
}

__global__ __launch_bounds__(256, 2) void out_gemm(
    const short* Hc, const short* Wot, const float* bo, float* out) {
  gemm_body(Hc, Wot, bo, out, 0);
}

// ---------------------------------------------------------------------------
// Fused attention. Block = (b, h, 32 q-rows); 512 blocks; 4 waves
// (wi = i-half of 16 rows, wj = j/K-half). 64 pipelined phases:
//   phase p = jt*8 + ph;  ph<4: stage K_c tile (64j x 64d), score MFMAs,
//   exp, fenmu accumulate in regs; ph==3 tail writes R (bf16) to Rs LDS.
//   ph>=4: stage V_c^T tile (64d x 64j), R@V partial MFMAs (K-half per wj).
// Rotating double-buffered staging, one barrier per phase. XOR chunk swizzle
// (col^row&7) makes fragment ds_read_b128 <=2-way (free).
// Epilogue: cross-wj score reduction via 8KB xch, softmax(d=64), LN
// (unbiased std, eps on std), sum over c, +4*qh residual, bf16 Hc store.
// LDS: 16K stage + 4.6K Rs + 8K xch = 28.6 KB.
// ---------------------------------------------------------------------------
__global__ __launch_bounds__(256, 3) void attn2_kernel(
    const float* __restrict__ Qp, const short* __restrict__ Kb,
    const short* __restrict__ Vt, const float* __restrict__ alpha,
    const float* __restrict__ beta, short* __restrict__ Hc) {
  __shared__ __align__(16) short Stage[2][64 * 64];
  __shared__ __align__(16) short Rs[32][72];
  __shared__ __align__(16) float xch[16 * 128];

  const int it = blockIdx.x, h = blockIdx.y, b = blockIdx.z;
  const int i0 = it * 32;
  const int tid = threadIdx.x;
  const int w = tid >> 6, lane = tid & 63;
  const int l15 = lane & 15, q = lane >> 4;
  const int wi = w >> 1, wj = w & 1;
  const int wu = __builtin_amdgcn_readfirstlane(w);

  // Q A-fragments (rows i0 + wi*16 + l15), fp32 -> bf16, reused throughout.
  const float* qrow =
      Qp + (size_t)(b * SEQ + i0 + wi * 16 + l15) * DMODEL + h * DKH;
  const bf16x8 aq0 = cvt8(*(const float4*)(qrow + q * 8),
                          *(const float4*)(qrow + q * 8 + 4));
  const bf16x8 aq1 = cvt8(*(const float4*)(qrow + 32 + q * 8),
                          *(const float4*)(qrow + 32 + q * 8 + 4));

  // Staging lane constants: linear chunk s = (issue*4+wu)*64 + lane;
  // row = s>>3 (issue0: 0..31, issue1: 32..63), slot = lane&7,
  // logical chunk col = slot ^ (row&7)  (row&7 == lane>>3).
  const int srow0 = wu * 8 + (lane >> 3);
  const int scol = (lane & 7) ^ (lane >> 3);

  f32x4 acc[4][4] = {};          // Phase-B partial scores [c][nt]
  float sacc[2][4], ebb[2][4];   // per-jt fenmu accum / diagonal exps

  // prologue: stage phase 0 (K_0, jt=0)
  {
    const short* base = Kb + (size_t)(0 * SEQ) * DMODEL + h * DKH;
    async_cp16(base + (size_t)srow0 * DMODEL + scol * 8, &Stage[0][wu * 512]);
    async_cp16(base + (size_t)(srow0 + 32) * DMODEL + scol * 8,
               &Stage[0][(4 + wu) * 512]);
  }

  for (int p = 0; p < 64; ++p) {
    __syncthreads();  // drains stage(p); all waves done with buf[(p+1)&1]
    if (p < 63) {     // stage(p+1) overlaps compute(p)
      const int pn = p + 1;
      const int jt = pn >> 3, ph = pn & 7, j0 = jt << 6;
      const short* g0;
      size_t rstride;
      if (ph < 4) {
        g0 = Kb + (size_t)(ph * SEQ + j0) * DMODEL + h * DKH;
        rstride = DMODEL;
      } else {
        g0 = Vt + (((size_t)(((ph - 4) * NHEAD + h) * DKH)) << 9) + j0;
        rstride = SEQ;
      }
      const int buf = pn & 1;
      async_cp16(g0 + (size_t)srow0 * rstride + scol * 8,
                 &Stage[buf][wu * 512]);
      async_cp16(g0 + (size_t)(srow0 + 32) * rstride + scol * 8,
                 &Stage[buf][(4 + wu) * 512]);
    }
    const int jt = p >> 3, ph = p & 7;
    const short* S = Stage[p & 1];
    if (ph < 4) {
      // ---- Phase A: scores for c = ph, this jt's 64 j-columns ----
      const int c = ph;
      if (c == 0) {
#pragma unroll
        for (int t = 0; t < 2; ++t)
#pragma unroll
          for (int r = 0; r < 4; ++r) sacc[t][r] = 0.0f;
      }
#pragma unroll
      for (int ntl = 0; ntl < 2; ++ntl) {
        const int row = (wj * 2 + ntl) * 16 + l15;  // j within tile
        const int ph0 = q ^ (l15 & 7);              // swizzled chunk (d lo)
        bf16x8 b0 = *(const bf16x8*)&S[row * 64 + ph0 * 8];
        bf16x8 b1 = *(const bf16x8*)&S[row * 64 + (ph0 ^ 4) * 8];
        f32x4 s = {};
        s = __builtin_amdgcn_mfma_f32_16x16x32_bf16(aq0, b0, s, 0, 0, 0);
        s = __builtin_amdgcn_mfma_f32_16x16x32_bf16(aq1, b1, s, 0, 0, 0);
#pragma unroll
        for (int r = 0; r < 4; ++r) {
          const float e = __expf(s[r]);  // scores |.|<~10: safe, no max-sub
          sacc[ntl][r] += e;
          if (c == b) ebb[ntl][r] = e;
        }
      }
      if (c == 3) {  // fenmu complete: R = diag/(8*sum) -> Rs (bf16)
#pragma unroll
        for (int ntl = 0; ntl < 2; ++ntl)
#pragma unroll
          for (int r = 0; r < 4; ++r)
            Rs[wi * 16 + q * 4 + r][(wj * 2 + ntl) * 16 + l15] =
                f2bf(ebb[ntl][r] / (8.0f * sacc[ntl][r]));
      }
    } else {
      // ---- Phase B: partial score += R[:, wj-half] @ V_c ----
      const int c = ph - 4;
      bf16x8 ar = *(const bf16x8*)&Rs[wi * 16 + l15][wj * 32 + q * 8];
#pragma unroll
      for (int nt = 0; nt < 4; ++nt) {
        const int row = nt * 16 + l15;              // d within tile
        const int phb = (wj * 4 + q) ^ (l15 & 7);   // swizzled chunk (j)
        bf16x8 bv = *(const bf16x8*)&S[row * 64 + phb * 8];
        acc[c][nt] =
            __builtin_amdgcn_mfma_f32_16x16x32_bf16(ar, bv, acc[c][nt], 0, 0, 0);
      }
    }
  }

  // ---- cross-wj score reduction (K-halves) into wj==0 waves ----
  for (int c = 0; c < BSZ; ++c) {
    if (wj == 1) {
#pragma unroll
      for (int nt = 0; nt < 4; ++nt)
#pragma unroll
        for (int r = 0; r < 4; ++r)
          xch[(nt * 4 + r) * 128 + wi * 64 + lane] = acc[c][nt][r];
    }
    __syncthreads();
    if (wj == 0) {
#pragma unroll
      for (int nt = 0; nt < 4; ++nt)
#pragma unroll
        for (int r = 0; r < 4; ++r)
          acc[c][nt][r] += xch[(nt * 4 + r) * 128 + wi * 64 + lane];
    }
    __syncthreads();
  }

  if (wj == 0) {
    float al[4], be[4];
#pragma unroll
    for (int nt = 0; nt < 4; ++nt) {
      al[nt] = alpha[nt * 16 + l15];
      be[nt] = beta[nt * 16 + l15];
    }
    float hacc[4][4] = {};  // [r][nt]
#pragma unroll
    for (int c = 0; c < BSZ; ++c) {
#pragma unroll
      for (int r = 0; r < 4; ++r) {
        float e0 = __expf(acc[c][0][r]), e1 = __expf(acc[c][1][r]);
        float e2 = __expf(acc[c][2][r]), e3 = __expf(acc[c][3][r]);
        float es = e0 + e1 + e2 + e3;
#pragma unroll
        for (int m = 8; m >= 1; m >>= 1) es += __shfl_xor(es, m);
        const float inv = 1.0f / es;
        const float d0 = e0 * inv - 0.015625f, d1 = e1 * inv - 0.015625f;
        const float d2 = e2 * inv - 0.015625f, d3 = e3 * inv - 0.015625f;
        float sq = d0 * d0 + d1 * d1 + d2 * d2 + d3 * d3;
#pragma unroll
        for (int m = 8; m >= 1; m >>= 1) sq += __shfl_xor(sq, m);
        const float rs = 1.0f / (sqrtf(sq * (1.0f / 63.0f)) + EPSLN);
        hacc[r][0] += al[0] * d0 * rs + be[0];
        hacc[r][1] += al[1] * d1 * rs + be[1];
        hacc[r][2] += al[2] * d2 * rs + be[2];
        hacc[r][3] += al[3] * d3 * rs + be[3];
      }
    }
    // + 4*qh residual, store Hc (bf16 [token][dmodel])
#pragma unroll
    for (int r = 0; r < 4; ++r) {
      const size_t rowoff =
          (size_t)(b * SEQ + i0 + wi * 16 + q * 4 + r) * DMODEL + h * DKH;
#pragma unroll
      for (int nt = 0; nt < 4; ++nt) {
        const int d = nt * 16 + l15;
        const float o = hacc[r][nt] + 4.0f * Qp[rowoff + d];
        Hc[rowoff + d] = f2bf(o);
      }
    }
  }
}

// ---------------------------------------------------------------------------
extern "C" void kernel_launch(void* const* d_in, const int* in_sizes, int n_in,
                              void* d_out, int out_size, void* d_ws,
                              size_t ws_size, hipStream_t stream) {
  (void)in_sizes; (void)n_in; (void)out_size; (void)ws_size;
  const float* q = (const float*)d_in[0];
  const float* k = (const float*)d_in[1];
  const float* v = (const float*)d_in[2];
  const float* Wq = (const float*)d_in[3];
  const float* bq = (const float*)d_in[4];
  const float* Wk = (const float*)d_in[5];
  const float* bk = (const float*)d_in[6];
  const float* Wv = (const float*)d_in[7];
  const float* bv = (const float*)d_in[8];
  const float* Wo = (const float*)d_in[9];
  const float* bo = (const float*)d_in[10];
  const float* alpha = (const float*)d_in[11];
  const float* beta = (const float*)d_in[12];
  float* out = (float*)d_out;

  // Workspace (bytes): qb|kb|vb bf16 2MB ea @0/2/4M; Qp fp32 4MB @6M;
  // Kb bf16 2MB @10M; Vt bf16 2MB @12M; Hc bf16 2MB @14M; Wt's 0.5MB ea @16M+
  char* wsb = (char*)d_ws;
  short* qb = (short*)(wsb);
  short* kb = (short*)(wsb + (2u << 20));
  short* vb = (short*)(wsb + (4u << 20));
  float* Qp = (float*)(wsb + (6u << 20));
  short* Kb = (short*)(wsb + (10u << 20));
  short* Vtg = (short*)(wsb + (12u << 20));
  short* Hc = (short*)(wsb + (14u << 20));
  short* Wqt = (short*)(wsb + (16u << 20));
  short* Wkt = (short*)(wsb + (16u << 20) + (512u << 10));
  short* Wvt = (short*)(wsb + (17u << 20));
  short* Wot = (short*)(wsb + (17u << 20) + (512u << 10));

  cast3_kernel<<<dim3(512, 3), 256, 0, stream>>>(q, k, v, qb, kb, vb);
  wcast_kernel<<<dim3(8, 8, 4), 256, 0, stream>>>(Wq, Wk, Wv, Wo,
                                                  Wqt, Wkt, Wvt, Wot);
  proj_gemm<<<dim3(4, 16, 3), 256, 0, stream>>>(qb, kb, vb, Wqt, Wkt, Wvt,
                                                bq, bk, bv, Qp, Kb, Vtg);
  attn2_kernel<<<dim3(16, 8, 4), 256, 0, stream>>>(Qp, Kb, Vtg, alpha, beta,
                                                   Hc);
  out_gemm<<<dim3(4, 16), 256, 0, stream>>>(Hc, Wot, bo, out);
}

// Round 4
// 161.038 us; speedup vs baseline: 1.3767x; 1.3767x over previous
//
#include <hip/hip_runtime.h>
#include <hip/hip_bf16.h>

// Problem constants (fixed by the reference).
#define BSZ 4
#define SEQ 512
#define DMODEL 512
#define NHEAD 8
#define DKH 64
#define EPSLN 1e-6f

typedef short bf16x8 __attribute__((ext_vector_type(8)));
typedef float f32x4 __attribute__((ext_vector_type(4)));

// fp32 -> bf16 round-to-nearest-even
static __device__ __forceinline__ short f2bf(float x) {
  unsigned u = __builtin_bit_cast(unsigned, x);
  u = (u + 0x7FFFu + ((u >> 16) & 1u)) >> 16;
  return (short)u;
}
static __device__ __forceinline__ bf16x8 cvt8(float4 a, float4 b) {
  bf16x8 r;
  r[0] = f2bf(a.x); r[1] = f2bf(a.y); r[2] = f2bf(a.z); r[3] = f2bf(a.w);
  r[4] = f2bf(b.x); r[5] = f2bf(b.y); r[6] = f2bf(b.z); r[7] = f2bf(b.w);
  return r;
}
static __device__ __forceinline__ unsigned pk2(float a, float b) {
  return (unsigned)(unsigned short)f2bf(a) |
         ((unsigned)(unsigned short)f2bf(b) << 16);
}
// async 16B/lane global -> LDS (lds dest = wave-uniform base + lane*16)
static __device__ __forceinline__ void async_cp16(const void* g, void* l) {
  __builtin_amdgcn_global_load_lds(
      (const __attribute__((address_space(1))) unsigned int*)g,
      (__attribute__((address_space(3))) unsigned int*)l, 16, 0, 0);
}

// ---------------------------------------------------------------------------
// Cast q,k,v (fp32) -> bf16.
// ---------------------------------------------------------------------------
__global__ __launch_bounds__(256) void cast3_kernel(
    const float* __restrict__ q, const float* __restrict__ k,
    const float* __restrict__ v, short* __restrict__ qb,
    short* __restrict__ kb, short* __restrict__ vb) {
  const float* s; short* d;
  switch (blockIdx.y) {
    case 0: s = q; d = qb; break;
    case 1: s = k; d = kb; break;
    default: s = v; d = vb; break;
  }
  const size_t idx = (size_t)blockIdx.x * 2048 + (size_t)threadIdx.x * 8;
  float4 a = *(const float4*)&s[idx];
  float4 b = *(const float4*)&s[idx + 4];
  *(bf16x8*)&d[idx] = cvt8(a, b);
}

// ---------------------------------------------------------------------------
// W (fp32, [K][N]) -> W^T (bf16, [N][K]).
// ---------------------------------------------------------------------------
__global__ __launch_bounds__(256) void wcast_kernel(
    const float* __restrict__ Wq, const float* __restrict__ Wk,
    const float* __restrict__ Wv, const float* __restrict__ Wo,
    short* __restrict__ Wqt, short* __restrict__ Wkt,
    short* __restrict__ Wvt, short* __restrict__ Wot) {
  __shared__ float T[64][65];
  const float* src; short* dst;
  switch (blockIdx.z) {
    case 0: src = Wq; dst = Wqt; break;
    case 1: src = Wk; dst = Wkt; break;
    case 2: src = Wv; dst = Wvt; break;
    default: src = Wo; dst = Wot; break;
  }
  const int k0 = blockIdx.x * 64, n0 = blockIdx.y * 64;
  const int tid = threadIdx.x;
  const int n4 = (tid & 15) * 4, kk = tid >> 4;
#pragma unroll
  for (int p = 0; p < 4; ++p) {
    float4 v = *(const float4*)&src[(size_t)(k0 + kk + p * 16) * DMODEL + n0 + n4];
    T[kk + p * 16][n4 + 0] = v.x;
    T[kk + p * 16][n4 + 1] = v.y;
    T[kk + p * 16][n4 + 2] = v.z;
    T[kk + p * 16][n4 + 3] = v.w;
  }
  __syncthreads();
  const int k4 = (tid & 15) * 4;
#pragma unroll
  for (int p = 0; p < 4; ++p) {
    const int nn = (tid >> 4) + p * 16;
    float x0 = T[k4 + 0][nn], x1 = T[k4 + 1][nn];
    float x2 = T[k4 + 2][nn], x3 = T[k4 + 3][nn];
    uint2 u; u.x = pk2(x0, x1); u.y = pk2(x2, x3);
    *(uint2*)&dst[(size_t)(n0 + nn) * DMODEL + k0 + k4] = u;
  }
}

// ---------------------------------------------------------------------------
// m97-style GEMM body: C[128x128] = A(bf16 [M][512]) @ Wt(bf16 [N][512])^T
// + bias. Rotating double-buffer, one barrier per k-step.
// ---------------------------------------------------------------------------
__device__ __forceinline__ void gemm_body(
    const short* __restrict__ A, const short* __restrict__ Wt,
    const float* __restrict__ bias, void* __restrict__ out, int omode) {
  __shared__ short As[2][128 * 32];
  __shared__ short Bs[2][128 * 32];
  const int tid = threadIdx.x;
  const int w = tid >> 6, lane = tid & 63;
  const int l15 = lane & 15, q = lane >> 4;
  const int wm = w >> 1, wn = w & 1;
  const int bn = blockIdx.x * 128, bm = blockIdx.y * 128;
  const int wu = __builtin_amdgcn_readfirstlane(w);
  const int srow = wu * 16 + (lane >> 2);
  const int sch = lane & 3;

  f32x4 acc[4][4] = {};

#define GSTAGE(k0, buf)                                                      \
  {                                                                          \
    const short* ga0 = A + (size_t)(bm + srow) * 512 + (k0) + sch * 8;       \
    const short* ga1 = A + (size_t)(bm + srow + 64) * 512 + (k0) + sch * 8;  \
    const short* gb0 = Wt + (size_t)(bn + srow) * 512 + (k0) + sch * 8;      \
    const short* gb1 = Wt + (size_t)(bn + srow + 64) * 512 + (k0) + sch * 8; \
    async_cp16(ga0, &As[buf][wu * 512]);                                     \
    async_cp16(ga1, &As[buf][(4 + wu) * 512]);                               \
    async_cp16(gb0, &Bs[buf][wu * 512]);                                     \
    async_cp16(gb1, &Bs[buf][(4 + wu) * 512]);                               \
  }

  GSTAGE(0, 0);
  for (int ks = 0; ks < 16; ++ks) {
    __syncthreads();
    if (ks < 15) GSTAGE((ks + 1) * 32, (ks + 1) & 1);
    const short* a = As[ks & 1];
    const short* bsh = Bs[ks & 1];
    bf16x8 af[4], bfr[4];
#pragma unroll
    for (int mt = 0; mt < 4; ++mt)
      af[mt] = *(const bf16x8*)&a[(wm * 64 + mt * 16 + l15) * 32 + q * 8];
#pragma unroll
    for (int nt = 0; nt < 4; ++nt)
      bfr[nt] = *(const bf16x8*)&bsh[(wn * 64 + nt * 16 + l15) * 32 + q * 8];
#pragma unroll
    for (int mt = 0; mt < 4; ++mt)
#pragma unroll
      for (int nt = 0; nt < 4; ++nt)
        acc[mt][nt] = __builtin_amdgcn_mfma_f32_16x16x32_bf16(
            af[mt], bfr[nt], acc[mt][nt], 0, 0, 0);
  }
#undef GSTAGE

  float bv[4];
#pragma unroll
  for (int nt = 0; nt < 4; ++nt) bv[nt] = bias[bn + wn * 64 + nt * 16 + l15];
#pragma unroll
  for (int mt = 0; mt < 4; ++mt)
#pragma unroll
    for (int nt = 0; nt < 4; ++nt) {
      const int col = bn + wn * 64 + nt * 16 + l15;
#pragma unroll
      for (int r = 0; r < 4; ++r) {
        const int row = bm + wm * 64 + mt * 16 + q * 4 + r;
        const float val = acc[mt][nt][r] + bv[nt];
        if (omode == 0) {
          ((float*)out)[(size_t)row * 512 + col] = val;
        } else if (omode == 1) {
          ((short*)out)[(size_t)row * 512 + col] = f2bf(val);
        } else {
          const int cc = row >> 9, j = row & 511;
          const int hh = col >> 6, d = col & 63;
          ((short*)out)[(((size_t)(cc * 8 + hh) * 64 + d) << 9) + j] = f2bf(val);
        }
      }
    }
}

__global__ __launch_bounds__(256, 2) void proj_gemm(
    const short* qb, const short* kb, const short* vb,
    const short* Wqt, const short* Wkt, const short* Wvt,
    const float* bq, const float* bk, const float* bvs,
    float* Qp, short* Kb, short* Vt) {
  const short* A; const short* Wt; const float* bias; void* out; int omode;
  switch (blockIdx.z) {
    case 0: A = qb; Wt = Wqt; bias = bq; out = Qp; omode = 0; break;
    case 1: A = kb; Wt = Wkt; bias = bk; out = Kb; omode = 1; break;
    default: A = vb; Wt = Wvt; bias = bvs; out = Vt; omode = 2; break;
  }
  gemm_body(A, Wt, bias, out, omode);
}

__global__ __launch_bounds__(256, 2) void out_gemm(
    const short* Hc, const short* Wot, const float* bo, float* out) {
  gemm_body(Hc, Wot, bo, out, 0);
}

// ---------------------------------------------------------------------------
// Fused attention. Block = (b, h, 32 q-rows); 512 blocks; 4 waves
// (wi = i-half, wj = K-split half). 64 pipelined phases = jt(8) x ph(8);
// ph is FULLY UNROLLED so every acc[] index is compile-time (R3's runtime-c
// indexing spilled the 64-reg accumulator to scratch: 310 MB HBM writes).
//   ph<4:  stage K_c tile, QK^T MFMAs, exp, fenmu accum in regs (c==ph).
//   ph==3 tail: R = diag/(8*fenmu) -> bf16 Rs tile.
//   ph>=4: stage V_c^T tile, partial R@V MFMAs into acc[ph-4][*].
// Rotating double-buffer, one barrier per phase; XOR chunk swizzle on tiles.
// Epilogue: cross-wj reduction via xch, softmax(64) + LN, sum c, +4*qh.
// ---------------------------------------------------------------------------
__global__ __launch_bounds__(256, 3) void attn2_kernel(
    const float* __restrict__ Qp, const short* __restrict__ Kb,
    const short* __restrict__ Vt, const float* __restrict__ alpha,
    const float* __restrict__ beta, short* __restrict__ Hc) {
  __shared__ __align__(16) short Stage[2][64 * 64];
  __shared__ __align__(16) short Rs[32][72];
  __shared__ __align__(16) float xch[16 * 128];

  const int it = blockIdx.x, h = blockIdx.y, b = blockIdx.z;
  const int i0 = it * 32;
  const int tid = threadIdx.x;
  const int w = tid >> 6, lane = tid & 63;
  const int l15 = lane & 15, q = lane >> 4;
  const int wi = w >> 1, wj = w & 1;
  const int wu = __builtin_amdgcn_readfirstlane(w);

  // Q A-fragments (rows i0 + wi*16 + l15), fp32 -> bf16, reused throughout.
  const float* qrow =
      Qp + (size_t)(b * SEQ + i0 + wi * 16 + l15) * DMODEL + h * DKH;
  const bf16x8 aq0 = cvt8(*(const float4*)(qrow + q * 8),
                          *(const float4*)(qrow + q * 8 + 4));
  const bf16x8 aq1 = cvt8(*(const float4*)(qrow + 32 + q * 8),
                          *(const float4*)(qrow + 32 + q * 8 + 4));

  // Staging lane constants: issue0 rows 0..31, issue1 rows 32..63;
  // physical slot lane&7 holds logical chunk (lane&7)^(row&7), row&7=lane>>3.
  const int srow0 = wu * 8 + (lane >> 3);
  const int scol = (lane & 7) ^ (lane >> 3);

  const short* kbase_h = Kb + h * DKH;
  const short* vbase_h = Vt + (((size_t)h * DKH) << 9);

  // stage helper: 64x64 bf16 tile rows at g0 with row stride rstride.
#define STG(g0, rstride, buf)                                             \
  {                                                                       \
    async_cp16((g0) + (size_t)srow0 * (rstride) + scol * 8,               \
               &Stage[buf][wu * 512]);                                    \
    async_cp16((g0) + (size_t)(srow0 + 32) * (rstride) + scol * 8,        \
               &Stage[buf][(4 + wu) * 512]);                              \
  }

  f32x4 acc[4][4] = {};          // Phase-B partial scores [c][nt] (static idx)
  float sacc[2][4], ebb[2][4];

  // prologue: stage (jt=0, ph=0) = K_0 tile
  STG(kbase_h, DMODEL, 0);

  for (int jt = 0; jt < 8; ++jt) {
    const int j0 = jt * 64;
    bf16x8 ar;  // R A-fragment for this jt (loaded at ph==4)
#pragma unroll
    for (int ph = 0; ph < 8; ++ph) {
      __syncthreads();  // drains stage(jt,ph); frees buf (ph^1)
      const int buf = ph & 1, nbuf = buf ^ 1;
      // ---- stage next phase (overlaps this phase's compute) ----
      if (ph < 3) {
        STG(kbase_h + ((size_t)((ph + 1) * SEQ) + j0) * DMODEL, DMODEL, nbuf);
      } else if (ph < 7) {
        const int cn = ph - 3;  // next V batch
        STG(vbase_h + (((size_t)(cn * NHEAD * DKH)) << 9) + j0, SEQ, nbuf);
      } else if (jt < 7) {
        STG(kbase_h + (size_t)(j0 + 64) * DMODEL, DMODEL, nbuf);
      }
      const short* S = Stage[buf];
      if (ph < 4) {
        // ---- Phase A: scores for c = ph (compile-time) ----
        if (ph == 0) {
#pragma unroll
          for (int t = 0; t < 2; ++t)
#pragma unroll
            for (int r = 0; r < 4; ++r) sacc[t][r] = 0.0f;
        }
#pragma unroll
        for (int ntl = 0; ntl < 2; ++ntl) {
          const int row = (wj * 2 + ntl) * 16 + l15;
          const int p0 = q ^ (l15 & 7);
          bf16x8 b0 = *(const bf16x8*)&S[row * 64 + p0 * 8];
          bf16x8 b1 = *(const bf16x8*)&S[row * 64 + (p0 ^ 4) * 8];
          f32x4 s = {};
          s = __builtin_amdgcn_mfma_f32_16x16x32_bf16(aq0, b0, s, 0, 0, 0);
          s = __builtin_amdgcn_mfma_f32_16x16x32_bf16(aq1, b1, s, 0, 0, 0);
#pragma unroll
          for (int r = 0; r < 4; ++r) {
            const float e = __expf(s[r]);
            sacc[ntl][r] += e;
            if (ph == b) ebb[ntl][r] = e;
          }
        }
        if (ph == 3) {  // fenmu complete -> R tile (bf16)
#pragma unroll
          for (int ntl = 0; ntl < 2; ++ntl)
#pragma unroll
            for (int r = 0; r < 4; ++r)
              Rs[wi * 16 + q * 4 + r][(wj * 2 + ntl) * 16 + l15] =
                  f2bf(ebb[ntl][r] / (8.0f * sacc[ntl][r]));
        }
      } else {
        // ---- Phase B: acc[c] += R[:, wj-half] @ V_c, c = ph-4 static ----
        if (ph == 4) ar = *(const bf16x8*)&Rs[wi * 16 + l15][wj * 32 + q * 8];
#pragma unroll
        for (int nt = 0; nt < 4; ++nt) {
          const int row = nt * 16 + l15;
          const int pb = (wj * 4 + q) ^ (l15 & 7);
          bf16x8 bv = *(const bf16x8*)&S[row * 64 + pb * 8];
          acc[ph - 4][nt] = __builtin_amdgcn_mfma_f32_16x16x32_bf16(
              ar, bv, acc[ph - 4][nt], 0, 0, 0);
        }
      }
    }
  }
#undef STG

  // ---- cross-wj score reduction (K-halves) into wj==0 waves ----
#pragma unroll
  for (int c = 0; c < BSZ; ++c) {
    if (wj == 1) {
#pragma unroll
      for (int nt = 0; nt < 4; ++nt)
#pragma unroll
        for (int r = 0; r < 4; ++r)
          xch[(nt * 4 + r) * 128 + wi * 64 + lane] = acc[c][nt][r];
    }
    __syncthreads();
    if (wj == 0) {
#pragma unroll
      for (int nt = 0; nt < 4; ++nt)
#pragma unroll
        for (int r = 0; r < 4; ++r)
          acc[c][nt][r] += xch[(nt * 4 + r) * 128 + wi * 64 + lane];
    }
    __syncthreads();
  }

  if (wj == 0) {
    float al[4], be[4];
#pragma unroll
    for (int nt = 0; nt < 4; ++nt) {
      al[nt] = alpha[nt * 16 + l15];
      be[nt] = beta[nt * 16 + l15];
    }
    float hacc[4][4] = {};  // [r][nt]
#pragma unroll
    for (int c = 0; c < BSZ; ++c) {
#pragma unroll
      for (int r = 0; r < 4; ++r) {
        float e0 = __expf(acc[c][0][r]), e1 = __expf(acc[c][1][r]);
        float e2 = __expf(acc[c][2][r]), e3 = __expf(acc[c][3][r]);
        float es = e0 + e1 + e2 + e3;
#pragma unroll
        for (int m = 8; m >= 1; m >>= 1) es += __shfl_xor(es, m);
        const float inv = 1.0f / es;
        const float d0 = e0 * inv - 0.015625f, d1 = e1 * inv - 0.015625f;
        const float d2 = e2 * inv - 0.015625f, d3 = e3 * inv - 0.015625f;
        float sq = d0 * d0 + d1 * d1 + d2 * d2 + d3 * d3;
#pragma unroll
        for (int m = 8; m >= 1; m >>= 1) sq += __shfl_xor(sq, m);
        const float rs = 1.0f / (sqrtf(sq * (1.0f / 63.0f)) + EPSLN);
        hacc[r][0] += al[0] * d0 * rs + be[0];
        hacc[r][1] += al[1] * d1 * rs + be[1];
        hacc[r][2] += al[2] * d2 * rs + be[2];
        hacc[r][3] += al[3] * d3 * rs + be[3];
      }
    }
#pragma unroll
    for (int r = 0; r < 4; ++r) {
      const size_t rowoff =
          (size_t)(b * SEQ + i0 + wi * 16 + q * 4 + r) * DMODEL + h * DKH;
#pragma unroll
      for (int nt = 0; nt < 4; ++nt) {
        const int d = nt * 16 + l15;
        const float o = hacc[r][nt] + 4.0f * Qp[rowoff + d];
        Hc[rowoff + d] = f2bf(o);
      }
    }
  }
}

// ---------------------------------------------------------------------------
extern "C" void kernel_launch(void* const* d_in, const int* in_sizes, int n_in,
                              void* d_out, int out_size, void* d_ws,
                              size_t ws_size, hipStream_t stream) {
  (void)in_sizes; (void)n_in; (void)out_size; (void)ws_size;
  const float* q = (const float*)d_in[0];
  const float* k = (const float*)d_in[1];
  const float* v = (const float*)d_in[2];
  const float* Wq = (const float*)d_in[3];
  const float* bq = (const float*)d_in[4];
  const float* Wk = (const float*)d_in[5];
  const float* bk = (const float*)d_in[6];
  const float* Wv = (const float*)d_in[7];
  const float* bv = (const float*)d_in[8];
  const float* Wo = (const float*)d_in[9];
  const float* bo = (const float*)d_in[10];
  const float* alpha = (const float*)d_in[11];
  const float* beta = (const float*)d_in[12];
  float* out = (float*)d_out;

  char* wsb = (char*)d_ws;
  short* qb = (short*)(wsb);
  short* kb = (short*)(wsb + (2u << 20));
  short* vb = (short*)(wsb + (4u << 20));
  float* Qp = (float*)(wsb + (6u << 20));
  short* Kb = (short*)(wsb + (10u << 20));
  short* Vtg = (short*)(wsb + (12u << 20));
  short* Hc = (short*)(wsb + (14u << 20));
  short* Wqt = (short*)(wsb + (16u << 20));
  short* Wkt = (short*)(wsb + (16u << 20) + (512u << 10));
  short* Wvt = (short*)(wsb + (17u << 20));
  short* Wot = (short*)(wsb + (17u << 20) + (512u << 10));

  cast3_kernel<<<dim3(512, 3), 256, 0, stream>>>(q, k, v, qb, kb, vb);
  wcast_kernel<<<dim3(8, 8, 4), 256, 0, stream>>>(Wq, Wk, Wv, Wo,
                                                  Wqt, Wkt, Wvt, Wot);
  proj_gemm<<<dim3(4, 16, 3), 256, 0, stream>>>(qb, kb, vb, Wqt, Wkt, Wvt,
                                                bq, bk, bv, Qp, Kb, Vtg);
  attn2_kernel<<<dim3(16, 8, 4), 256, 0, stream>>>(Qp, Kb, Vtg, alpha, beta,
                                                   Hc);
  out_gemm<<<dim3(4, 16), 256, 0, stream>>>(Hc, Wot, bo, out);
}

// Round 5
// 150.228 us; speedup vs baseline: 1.4758x; 1.0720x over previous
//
#include <hip/hip_runtime.h>
#include <hip/hip_bf16.h>

// Problem constants (fixed by the reference).
#define BSZ 4
#define SEQ 512
#define DMODEL 512
#define NHEAD 8
#define DKH 64
#define EPSLN 1e-6f

typedef short bf16x8 __attribute__((ext_vector_type(8)));
typedef float f32x4 __attribute__((ext_vector_type(4)));

// fp32 -> bf16 round-to-nearest-even
static __device__ __forceinline__ short f2bf(float x) {
  unsigned u = __builtin_bit_cast(unsigned, x);
  u = (u + 0x7FFFu + ((u >> 16) & 1u)) >> 16;
  return (short)u;
}
static __device__ __forceinline__ bf16x8 cvt8(float4 a, float4 b) {
  bf16x8 r;
  r[0] = f2bf(a.x); r[1] = f2bf(a.y); r[2] = f2bf(a.z); r[3] = f2bf(a.w);
  r[4] = f2bf(b.x); r[5] = f2bf(b.y); r[6] = f2bf(b.z); r[7] = f2bf(b.w);
  return r;
}
static __device__ __forceinline__ unsigned pk2(float a, float b) {
  return (unsigned)(unsigned short)f2bf(a) |
         ((unsigned)(unsigned short)f2bf(b) << 16);
}
// async 16B/lane global -> LDS (lds dest = wave-uniform base + lane*16)
static __device__ __forceinline__ void async_cp16(const void* g, void* l) {
  __builtin_amdgcn_global_load_lds(
      (const __attribute__((address_space(1))) unsigned int*)g,
      (__attribute__((address_space(3))) unsigned int*)l, 16, 0, 0);
}

// ---------------------------------------------------------------------------
// Prep (one launch): blocks 0..1535 cast q/k/v fp32->bf16; blocks 1536..1791
// transpose+cast the four W's to bf16 [N][K].
// ---------------------------------------------------------------------------
__global__ __launch_bounds__(256) void prep_kernel(
    const float* __restrict__ q, const float* __restrict__ k,
    const float* __restrict__ v, short* __restrict__ qb,
    short* __restrict__ kb, short* __restrict__ vb,
    const float* __restrict__ Wq, const float* __restrict__ Wk,
    const float* __restrict__ Wv, const float* __restrict__ Wo,
    short* __restrict__ Wqt, short* __restrict__ Wkt,
    short* __restrict__ Wvt, short* __restrict__ Wot) {
  __shared__ float T[64][65];
  const int bx = blockIdx.x;
  if (bx < 1536) {
    const int which = bx >> 9, blk = bx & 511;
    const float* s; short* d;
    switch (which) {
      case 0: s = q; d = qb; break;
      case 1: s = k; d = kb; break;
      default: s = v; d = vb; break;
    }
    const size_t idx = (size_t)blk * 2048 + (size_t)threadIdx.x * 8;
    float4 a = *(const float4*)&s[idx];
    float4 b = *(const float4*)&s[idx + 4];
    *(bf16x8*)&d[idx] = cvt8(a, b);
    return;
  }
  const int r = bx - 1536;
  const int mat = r >> 6, m = r & 63;
  const int k0 = (m & 7) * 64, n0 = (m >> 3) * 64;
  const float* src; short* dst;
  switch (mat) {
    case 0: src = Wq; dst = Wqt; break;
    case 1: src = Wk; dst = Wkt; break;
    case 2: src = Wv; dst = Wvt; break;
    default: src = Wo; dst = Wot; break;
  }
  const int tid = threadIdx.x;
  const int n4 = (tid & 15) * 4, kk = tid >> 4;
#pragma unroll
  for (int p = 0; p < 4; ++p) {
    float4 w4 = *(const float4*)&src[(size_t)(k0 + kk + p * 16) * DMODEL + n0 + n4];
    T[kk + p * 16][n4 + 0] = w4.x;
    T[kk + p * 16][n4 + 1] = w4.y;
    T[kk + p * 16][n4 + 2] = w4.z;
    T[kk + p * 16][n4 + 3] = w4.w;
  }
  __syncthreads();
  const int k4 = (tid & 15) * 4;
#pragma unroll
  for (int p = 0; p < 4; ++p) {
    const int nn = (tid >> 4) + p * 16;
    float x0 = T[k4 + 0][nn], x1 = T[k4 + 1][nn];
    float x2 = T[k4 + 2][nn], x3 = T[k4 + 3][nn];
    uint2 u; u.x = pk2(x0, x1); u.y = pk2(x2, x3);
    *(uint2*)&dst[(size_t)(n0 + nn) * DMODEL + k0 + k4] = u;
  }
}

// ---------------------------------------------------------------------------
// m97-style GEMM body: C[128x128] = A(bf16 [M][512]) @ Wt(bf16 [N][512])^T
// + bias. Rotating double-buffer, one barrier per k-step.
// ---------------------------------------------------------------------------
__device__ __forceinline__ void gemm_body(
    const short* __restrict__ A, const short* __restrict__ Wt,
    const float* __restrict__ bias, void* __restrict__ out, int omode) {
  __shared__ short As[2][128 * 32];
  __shared__ short Bs[2][128 * 32];
  const int tid = threadIdx.x;
  const int w = tid >> 6, lane = tid & 63;
  const int l15 = lane & 15, q = lane >> 4;
  const int wm = w >> 1, wn = w & 1;
  const int bn = blockIdx.x * 128, bm = blockIdx.y * 128;
  const int wu = __builtin_amdgcn_readfirstlane(w);
  const int srow = wu * 16 + (lane >> 2);
  const int sch = lane & 3;

  f32x4 acc[4][4] = {};

#define GSTAGE(k0, buf)                                                      \
  {                                                                          \
    const short* ga0 = A + (size_t)(bm + srow) * 512 + (k0) + sch * 8;       \
    const short* ga1 = A + (size_t)(bm + srow + 64) * 512 + (k0) + sch * 8;  \
    const short* gb0 = Wt + (size_t)(bn + srow) * 512 + (k0) + sch * 8;      \
    const short* gb1 = Wt + (size_t)(bn + srow + 64) * 512 + (k0) + sch * 8; \
    async_cp16(ga0, &As[buf][wu * 512]);                                     \
    async_cp16(ga1, &As[buf][(4 + wu) * 512]);                               \
    async_cp16(gb0, &Bs[buf][wu * 512]);                                     \
    async_cp16(gb1, &Bs[buf][(4 + wu) * 512]);                               \
  }

  GSTAGE(0, 0);
  for (int ks = 0; ks < 16; ++ks) {
    __syncthreads();
    if (ks < 15) GSTAGE((ks + 1) * 32, (ks + 1) & 1);
    const short* a = As[ks & 1];
    const short* bsh = Bs[ks & 1];
    bf16x8 af[4], bfr[4];
#pragma unroll
    for (int mt = 0; mt < 4; ++mt)
      af[mt] = *(const bf16x8*)&a[(wm * 64 + mt * 16 + l15) * 32 + q * 8];
#pragma unroll
    for (int nt = 0; nt < 4; ++nt)
      bfr[nt] = *(const bf16x8*)&bsh[(wn * 64 + nt * 16 + l15) * 32 + q * 8];
#pragma unroll
    for (int mt = 0; mt < 4; ++mt)
#pragma unroll
      for (int nt = 0; nt < 4; ++nt)
        acc[mt][nt] = __builtin_amdgcn_mfma_f32_16x16x32_bf16(
            af[mt], bfr[nt], acc[mt][nt], 0, 0, 0);
  }
#undef GSTAGE

  float bv[4];
#pragma unroll
  for (int nt = 0; nt < 4; ++nt) bv[nt] = bias[bn + wn * 64 + nt * 16 + l15];
#pragma unroll
  for (int mt = 0; mt < 4; ++mt)
#pragma unroll
    for (int nt = 0; nt < 4; ++nt) {
      const int col = bn + wn * 64 + nt * 16 + l15;
#pragma unroll
      for (int r = 0; r < 4; ++r) {
        const int row = bm + wm * 64 + mt * 16 + q * 4 + r;
        const float val = acc[mt][nt][r] + bv[nt];
        if (omode == 0) {
          ((float*)out)[(size_t)row * 512 + col] = val;
        } else if (omode == 1) {
          ((short*)out)[(size_t)row * 512 + col] = f2bf(val);
        } else {
          const int cc = row >> 9, j = row & 511;
          const int hh = col >> 6, d = col & 63;
          ((short*)out)[(((size_t)(cc * 8 + hh) * 64 + d) << 9) + j] = f2bf(val);
        }
      }
    }
}

__global__ __launch_bounds__(256, 2) void proj_gemm(
    const short* qb, const short* kb, const short* vb,
    const short* Wqt, const short* Wkt, const short* Wvt,
    const float* bq, const float* bk, const float* bvs,
    float* Qp, short* Kb, short* Vt) {
  const short* A; const short* Wt; const float* bias; void* out; int omode;
  switch (blockIdx.z) {
    case 0: A = qb; Wt = Wqt; bias = bq; out = Qp; omode = 0; break;
    case 1: A = kb; Wt = Wkt; bias = bk; out = Kb; omode = 1; break;
    default: A = vb; Wt = Wvt; bias = bvs; out = Vt; omode = 2; break;
  }
  gemm_body(A, Wt, bias, out, omode);
}

__global__ __launch_bounds__(256, 2) void out_gemm(
    const short* Hc, const short* Wot, const float* bo, float* out) {
  gemm_body(Hc, Wot, bo, out, 0);
}

// ---------------------------------------------------------------------------
// Fused attention. Block = (b, h, 32 q-rows); 512 blocks; 4 waves
// (wi = i-half, wj = K-split half). Merged phases: per jt (8 j-tiles), FOUR
// barrier phases (was 8 in R4):
//   ph2=0: QK^T for c=0,1 (two 8KB K tiles in LDS)   [stage K c2,c3]
//   ph2=1: QK^T for c=2,3; R -> Rs (bf16)            [stage V c0,c1]
//   ph2=2: R@V partial for c=0,1                     [stage V c2,c3]
//   ph2=3: R@V partial for c=2,3                     [stage K(jt+1) c0,c1]
// 16KB staged per phase into rotating 2x16KB buffers; stage(p+1) issued right
// after the barrier so its latency overlaps compute(p). All acc[] indices
// compile-time (ph2/ct unrolled) — R3 lesson: runtime idx => scratch spill.
// Epilogue: cross-wj reduction via xch, softmax(64) + LN, sum c, +4*qh.
// LDS: 32K stage + 4.6K Rs + 8K xch = 44.6 KB.
// ---------------------------------------------------------------------------
__global__ __launch_bounds__(256, 3) void attn2_kernel(
    const float* __restrict__ Qp, const short* __restrict__ Kb,
    const short* __restrict__ Vt, const float* __restrict__ alpha,
    const float* __restrict__ beta, short* __restrict__ Hc) {
  __shared__ __align__(16) short Stage[2][2 * 4096];  // 2 bufs x 2 tiles
  __shared__ __align__(16) short Rs[32][72];
  __shared__ __align__(16) float xch[16 * 128];

  const int it = blockIdx.x, h = blockIdx.y, b = blockIdx.z;
  const int i0 = it * 32;
  const int tid = threadIdx.x;
  const int w = tid >> 6, lane = tid & 63;
  const int l15 = lane & 15, q = lane >> 4;
  const int wi = w >> 1, wj = w & 1;
  const int wu = __builtin_amdgcn_readfirstlane(w);

  // Q A-fragments (rows i0 + wi*16 + l15), fp32 -> bf16, reused throughout.
  const float* qrow =
      Qp + (size_t)(b * SEQ + i0 + wi * 16 + l15) * DMODEL + h * DKH;
  const bf16x8 aq0 = cvt8(*(const float4*)(qrow + q * 8),
                          *(const float4*)(qrow + q * 8 + 4));
  const bf16x8 aq1 = cvt8(*(const float4*)(qrow + 32 + q * 8),
                          *(const float4*)(qrow + 32 + q * 8 + 4));

  // Staging lane constants: issue0 rows 0..31, issue1 rows 32..63; physical
  // slot lane&7 holds logical chunk (lane&7)^(row&7), row&7 = lane>>3.
  const int srow0 = wu * 8 + (lane >> 3);
  const int scol = (lane & 7) ^ (lane >> 3);

  const short* kbase_h = Kb + h * DKH;
  const short* vbase_h = Vt + (((size_t)h * DKH) << 9);

  // stage one 64x64 bf16 tile (rows at g0, row-stride rs) into buf/tslot.
#define STG1(g0, rs, buf, tslot)                                          \
  {                                                                       \
    async_cp16((g0) + (size_t)srow0 * (rs) + scol * 8,                    \
               &Stage[buf][(tslot) * 4096 + wu * 512]);                   \
    async_cp16((g0) + (size_t)(srow0 + 32) * (rs) + scol * 8,             \
               &Stage[buf][(tslot) * 4096 + (4 + wu) * 512]);             \
  }
  // K tile for batch c, j-tile j0 / V^T tile for batch c, j-tile j0
#define KTILE(c, j0) (kbase_h + ((size_t)((c) * SEQ) + (j0)) * DMODEL)
#define VTILE(c, j0) (vbase_h + (((size_t)((c) * NHEAD * DKH)) << 9) + (j0))

  f32x4 acc[4][4] = {};          // R@V partials [c][nt] — static idx only
  float sacc[2][4], ebb[2][4];

  // prologue: stage K c0,c1 of jt=0 into buf 0
  STG1(KTILE(0, 0), DMODEL, 0, 0);
  STG1(KTILE(1, 0), DMODEL, 0, 1);

  for (int jt = 0; jt < 8; ++jt) {
    const int j0 = jt * 64;
    bf16x8 ar;  // R A-fragment for this jt (loaded at ph2==2)
#pragma unroll
    for (int ph2 = 0; ph2 < 4; ++ph2) {
      __syncthreads();  // drains stage(jt,ph2); frees buf (ph2^1)
      const int buf = ph2 & 1, nbuf = buf ^ 1;
      // ---- stage next phase (overlaps this phase's compute) ----
      if (ph2 == 0) {
        STG1(KTILE(2, j0), DMODEL, nbuf, 0);
        STG1(KTILE(3, j0), DMODEL, nbuf, 1);
      } else if (ph2 == 1) {
        STG1(VTILE(0, j0), SEQ, nbuf, 0);
        STG1(VTILE(1, j0), SEQ, nbuf, 1);
      } else if (ph2 == 2) {
        STG1(VTILE(2, j0), SEQ, nbuf, 0);
        STG1(VTILE(3, j0), SEQ, nbuf, 1);
      } else if (jt < 7) {
        STG1(KTILE(0, j0 + 64), DMODEL, nbuf, 0);
        STG1(KTILE(1, j0 + 64), DMODEL, nbuf, 1);
      }
      if (ph2 < 2) {
        // ---- QK^T for c = ph2*2, ph2*2+1 (compile-time) ----
        if (ph2 == 0) {
#pragma unroll
          for (int t = 0; t < 2; ++t)
#pragma unroll
            for (int r = 0; r < 4; ++r) { sacc[t][r] = 0.0f; ebb[t][r] = 0.0f; }
        }
#pragma unroll
        for (int ct = 0; ct < 2; ++ct) {
          const int c = ph2 * 2 + ct;
          const short* S = &Stage[buf][ct * 4096];
#pragma unroll
          for (int ntl = 0; ntl < 2; ++ntl) {
            const int row = (wj * 2 + ntl) * 16 + l15;
            const int p0 = q ^ (l15 & 7);
            bf16x8 b0 = *(const bf16x8*)&S[row * 64 + p0 * 8];
            bf16x8 b1 = *(const bf16x8*)&S[row * 64 + (p0 ^ 4) * 8];
            f32x4 s = {};
            s = __builtin_amdgcn_mfma_f32_16x16x32_bf16(aq0, b0, s, 0, 0, 0);
            s = __builtin_amdgcn_mfma_f32_16x16x32_bf16(aq1, b1, s, 0, 0, 0);
#pragma unroll
            for (int r = 0; r < 4; ++r) {
              const float e = __expf(s[r]);
              sacc[ntl][r] += e;
              ebb[ntl][r] = (c == b) ? e : ebb[ntl][r];
            }
          }
        }
        if (ph2 == 1) {  // fenmu complete -> R tile (bf16)
#pragma unroll
          for (int ntl = 0; ntl < 2; ++ntl)
#pragma unroll
            for (int r = 0; r < 4; ++r)
              Rs[wi * 16 + q * 4 + r][(wj * 2 + ntl) * 16 + l15] =
                  f2bf(ebb[ntl][r] / (8.0f * sacc[ntl][r]));
        }
      } else {
        // ---- R@V partial for c = (ph2-2)*2 + ct (compile-time) ----
        if (ph2 == 2) ar = *(const bf16x8*)&Rs[wi * 16 + l15][wj * 32 + q * 8];
#pragma unroll
        for (int ct = 0; ct < 2; ++ct) {
          const int c = (ph2 - 2) * 2 + ct;
          const short* S = &Stage[buf][ct * 4096];
#pragma unroll
          for (int nt = 0; nt < 4; ++nt) {
            const int row = nt * 16 + l15;
            const int pb = (wj * 4 + q) ^ (l15 & 7);
            bf16x8 bv = *(const bf16x8*)&S[row * 64 + pb * 8];
            acc[c][nt] = __builtin_amdgcn_mfma_f32_16x16x32_bf16(
                ar, bv, acc[c][nt], 0, 0, 0);
          }
        }
      }
    }
  }
#undef STG1
#undef KTILE
#undef VTILE

  // ---- cross-wj score reduction (K-halves) into wj==0 waves ----
#pragma unroll
  for (int c = 0; c < BSZ; ++c) {
    if (wj == 1) {
#pragma unroll
      for (int nt = 0; nt < 4; ++nt)
#pragma unroll
        for (int r = 0; r < 4; ++r)
          xch[(nt * 4 + r) * 128 + wi * 64 + lane] = acc[c][nt][r];
    }
    __syncthreads();
    if (wj == 0) {
#pragma unroll
      for (int nt = 0; nt < 4; ++nt)
#pragma unroll
        for (int r = 0; r < 4; ++r)
          acc[c][nt][r] += xch[(nt * 4 + r) * 128 + wi * 64 + lane];
    }
    __syncthreads();
  }

  if (wj == 0) {
    float al[4], be[4];
#pragma unroll
    for (int nt = 0; nt < 4; ++nt) {
      al[nt] = alpha[nt * 16 + l15];
      be[nt] = beta[nt * 16 + l15];
    }
    float hacc[4][4] = {};  // [r][nt]
#pragma unroll
    for (int c = 0; c < BSZ; ++c) {
#pragma unroll
      for (int r = 0; r < 4; ++r) {
        float e0 = __expf(acc[c][0][r]), e1 = __expf(acc[c][1][r]);
        float e2 = __expf(acc[c][2][r]), e3 = __expf(acc[c][3][r]);
        float es = e0 + e1 + e2 + e3;
#pragma unroll
        for (int m = 8; m >= 1; m >>= 1) es += __shfl_xor(es, m);
        const float inv = 1.0f / es;
        const float d0 = e0 * inv - 0.015625f, d1 = e1 * inv - 0.015625f;
        const float d2 = e2 * inv - 0.015625f, d3 = e3 * inv - 0.015625f;
        float sq = d0 * d0 + d1 * d1 + d2 * d2 + d3 * d3;
#pragma unroll
        for (int m = 8; m >= 1; m >>= 1) sq += __shfl_xor(sq, m);
        const float rs = 1.0f / (sqrtf(sq * (1.0f / 63.0f)) + EPSLN);
        hacc[r][0] += al[0] * d0 * rs + be[0];
        hacc[r][1] += al[1] * d1 * rs + be[1];
        hacc[r][2] += al[2] * d2 * rs + be[2];
        hacc[r][3] += al[3] * d3 * rs + be[3];
      }
    }
#pragma unroll
    for (int r = 0; r < 4; ++r) {
      const size_t rowoff =
          (size_t)(b * SEQ + i0 + wi * 16 + q * 4 + r) * DMODEL + h * DKH;
#pragma unroll
      for (int nt = 0; nt < 4; ++nt) {
        const int d = nt * 16 + l15;
        const float o = hacc[r][nt] + 4.0f * Qp[rowoff + d];
        Hc[rowoff + d] = f2bf(o);
      }
    }
  }
}

// ---------------------------------------------------------------------------
extern "C" void kernel_launch(void* const* d_in, const int* in_sizes, int n_in,
                              void* d_out, int out_size, void* d_ws,
                              size_t ws_size, hipStream_t stream) {
  (void)in_sizes; (void)n_in; (void)out_size; (void)ws_size;
  const float* q = (const float*)d_in[0];
  const float* k = (const float*)d_in[1];
  const float* v = (const float*)d_in[2];
  const float* Wq = (const float*)d_in[3];
  const float* bq = (const float*)d_in[4];
  const float* Wk = (const float*)d_in[5];
  const float* bk = (const float*)d_in[6];
  const float* Wv = (const float*)d_in[7];
  const float* bv = (const float*)d_in[8];
  const float* Wo = (const float*)d_in[9];
  const float* bo = (const float*)d_in[10];
  const float* alpha = (const float*)d_in[11];
  const float* beta = (const float*)d_in[12];
  float* out = (float*)d_out;

  char* wsb = (char*)d_ws;
  short* qb = (short*)(wsb);
  short* kb = (short*)(wsb + (2u << 20));
  short* vb = (short*)(wsb + (4u << 20));
  float* Qp = (float*)(wsb + (6u << 20));
  short* Kb = (short*)(wsb + (10u << 20));
  short* Vtg = (short*)(wsb + (12u << 20));
  short* Hc = (short*)(wsb + (14u << 20));
  short* Wqt = (short*)(wsb + (16u << 20));
  short* Wkt = (short*)(wsb + (16u << 20) + (512u << 10));
  short* Wvt = (short*)(wsb + (17u << 20));
  short* Wot = (short*)(wsb + (17u << 20) + (512u << 10));

  prep_kernel<<<dim3(1792), 256, 0, stream>>>(q, k, v, qb, kb, vb,
                                              Wq, Wk, Wv, Wo,
                                              Wqt, Wkt, Wvt, Wot);
  proj_gemm<<<dim3(4, 16, 3), 256, 0, stream>>>(qb, kb, vb, Wqt, Wkt, Wvt,
                                                bq, bk, bv, Qp, Kb, Vtg);
  attn2_kernel<<<dim3(16, 8, 4), 256, 0, stream>>>(Qp, Kb, Vtg, alpha, beta,
                                                   Hc);
  out_gemm<<<dim3(4, 16), 256, 0, stream>>>(Hc, Wot, bo, out);
}

// Round 6
// 149.622 us; speedup vs baseline: 1.4818x; 1.0040x over previous
//
#include <hip/hip_runtime.h>
#include <hip/hip_bf16.h>

// Problem constants (fixed by the reference).
#define BSZ 4
#define SEQ 512
#define DMODEL 512
#define NHEAD 8
#define DKH 64
#define EPSLN 1e-6f

typedef short bf16x8 __attribute__((ext_vector_type(8)));
typedef float f32x4 __attribute__((ext_vector_type(4)));

// fp32 -> bf16 round-to-nearest-even
static __device__ __forceinline__ short f2bf(float x) {
  unsigned u = __builtin_bit_cast(unsigned, x);
  u = (u + 0x7FFFu + ((u >> 16) & 1u)) >> 16;
  return (short)u;
}
static __device__ __forceinline__ bf16x8 cvt8(float4 a, float4 b) {
  bf16x8 r;
  r[0] = f2bf(a.x); r[1] = f2bf(a.y); r[2] = f2bf(a.z); r[3] = f2bf(a.w);
  r[4] = f2bf(b.x); r[5] = f2bf(b.y); r[6] = f2bf(b.z); r[7] = f2bf(b.w);
  return r;
}
static __device__ __forceinline__ unsigned pk2(float a, float b) {
  return (unsigned)(unsigned short)f2bf(a) |
         ((unsigned)(unsigned short)f2bf(b) << 16);
}
// async 16B/lane global -> LDS (lds dest = wave-uniform base + lane*16)
static __device__ __forceinline__ void async_cp16(const void* g, void* l) {
  __builtin_amdgcn_global_load_lds(
      (const __attribute__((address_space(1))) unsigned int*)g,
      (__attribute__((address_space(3))) unsigned int*)l, 16, 0, 0);
}

// ---------------------------------------------------------------------------
// Prep (one launch): blocks 0..1535 cast q/k/v fp32->bf16; blocks 1536..1791
// transpose+cast the four W's to bf16 [N][K].
// ---------------------------------------------------------------------------
__global__ __launch_bounds__(256) void prep_kernel(
    const float* __restrict__ q, const float* __restrict__ k,
    const float* __restrict__ v, short* __restrict__ qb,
    short* __restrict__ kb, short* __restrict__ vb,
    const float* __restrict__ Wq, const float* __restrict__ Wk,
    const float* __restrict__ Wv, const float* __restrict__ Wo,
    short* __restrict__ Wqt, short* __restrict__ Wkt,
    short* __restrict__ Wvt, short* __restrict__ Wot) {
  __shared__ float T[64][65];
  const int bx = blockIdx.x;
  if (bx < 1536) {
    const int which = bx >> 9, blk = bx & 511;
    const float* s; short* d;
    switch (which) {
      case 0: s = q; d = qb; break;
      case 1: s = k; d = kb; break;
      default: s = v; d = vb; break;
    }
    const size_t idx = (size_t)blk * 2048 + (size_t)threadIdx.x * 8;
    float4 a = *(const float4*)&s[idx];
    float4 b = *(const float4*)&s[idx + 4];
    *(bf16x8*)&d[idx] = cvt8(a, b);
    return;
  }
  const int r = bx - 1536;
  const int mat = r >> 6, m = r & 63;
  const int k0 = (m & 7) * 64, n0 = (m >> 3) * 64;
  const float* src; short* dst;
  switch (mat) {
    case 0: src = Wq; dst = Wqt; break;
    case 1: src = Wk; dst = Wkt; break;
    case 2: src = Wv; dst = Wvt; break;
    default: src = Wo; dst = Wot; break;
  }
  const int tid = threadIdx.x;
  const int n4 = (tid & 15) * 4, kk = tid >> 4;
#pragma unroll
  for (int p = 0; p < 4; ++p) {
    float4 w4 = *(const float4*)&src[(size_t)(k0 + kk + p * 16) * DMODEL + n0 + n4];
    T[kk + p * 16][n4 + 0] = w4.x;
    T[kk + p * 16][n4 + 1] = w4.y;
    T[kk + p * 16][n4 + 2] = w4.z;
    T[kk + p * 16][n4 + 3] = w4.w;
  }
  __syncthreads();
  const int k4 = (tid & 15) * 4;
#pragma unroll
  for (int p = 0; p < 4; ++p) {
    const int nn = (tid >> 4) + p * 16;
    float x0 = T[k4 + 0][nn], x1 = T[k4 + 1][nn];
    float x2 = T[k4 + 2][nn], x3 = T[k4 + 3][nn];
    uint2 u; u.x = pk2(x0, x1); u.y = pk2(x2, x3);
    *(uint2*)&dst[(size_t)(n0 + nn) * DMODEL + k0 + k4] = u;
  }
}

// ---------------------------------------------------------------------------
// m97-style GEMM body: C[128x128] = A(bf16 [M][512]) @ Wt(bf16 [N][512])^T
// + bias. Rotating double-buffer, one barrier per k-step.
// ---------------------------------------------------------------------------
__device__ __forceinline__ void gemm_body(
    const short* __restrict__ A, const short* __restrict__ Wt,
    const float* __restrict__ bias, void* __restrict__ out, int omode) {
  __shared__ short As[2][128 * 32];
  __shared__ short Bs[2][128 * 32];
  const int tid = threadIdx.x;
  const int w = tid >> 6, lane = tid & 63;
  const int l15 = lane & 15, q = lane >> 4;
  const int wm = w >> 1, wn = w & 1;
  const int bn = blockIdx.x * 128, bm = blockIdx.y * 128;
  const int wu = __builtin_amdgcn_readfirstlane(w);
  const int srow = wu * 16 + (lane >> 2);
  const int sch = lane & 3;

  f32x4 acc[4][4] = {};

#define GSTAGE(k0, buf)                                                      \
  {                                                                          \
    const short* ga0 = A + (size_t)(bm + srow) * 512 + (k0) + sch * 8;       \
    const short* ga1 = A + (size_t)(bm + srow + 64) * 512 + (k0) + sch * 8;  \
    const short* gb0 = Wt + (size_t)(bn + srow) * 512 + (k0) + sch * 8;      \
    const short* gb1 = Wt + (size_t)(bn + srow + 64) * 512 + (k0) + sch * 8; \
    async_cp16(ga0, &As[buf][wu * 512]);                                     \
    async_cp16(ga1, &As[buf][(4 + wu) * 512]);                               \
    async_cp16(gb0, &Bs[buf][wu * 512]);                                     \
    async_cp16(gb1, &Bs[buf][(4 + wu) * 512]);                               \
  }

  GSTAGE(0, 0);
  for (int ks = 0; ks < 16; ++ks) {
    __syncthreads();
    if (ks < 15) GSTAGE((ks + 1) * 32, (ks + 1) & 1);
    const short* a = As[ks & 1];
    const short* bsh = Bs[ks & 1];
    bf16x8 af[4], bfr[4];
#pragma unroll
    for (int mt = 0; mt < 4; ++mt)
      af[mt] = *(const bf16x8*)&a[(wm * 64 + mt * 16 + l15) * 32 + q * 8];
#pragma unroll
    for (int nt = 0; nt < 4; ++nt)
      bfr[nt] = *(const bf16x8*)&bsh[(wn * 64 + nt * 16 + l15) * 32 + q * 8];
#pragma unroll
    for (int mt = 0; mt < 4; ++mt)
#pragma unroll
      for (int nt = 0; nt < 4; ++nt)
        acc[mt][nt] = __builtin_amdgcn_mfma_f32_16x16x32_bf16(
            af[mt], bfr[nt], acc[mt][nt], 0, 0, 0);
  }
#undef GSTAGE

  float bv[4];
#pragma unroll
  for (int nt = 0; nt < 4; ++nt) bv[nt] = bias[bn + wn * 64 + nt * 16 + l15];
#pragma unroll
  for (int mt = 0; mt < 4; ++mt)
#pragma unroll
    for (int nt = 0; nt < 4; ++nt) {
      const int col = bn + wn * 64 + nt * 16 + l15;
#pragma unroll
      for (int r = 0; r < 4; ++r) {
        const int row = bm + wm * 64 + mt * 16 + q * 4 + r;
        const float val = acc[mt][nt][r] + bv[nt];
        if (omode == 0) {
          ((float*)out)[(size_t)row * 512 + col] = val;
        } else if (omode == 1) {
          ((short*)out)[(size_t)row * 512 + col] = f2bf(val);
        } else {
          const int cc = row >> 9, j = row & 511;
          const int hh = col >> 6, d = col & 63;
          ((short*)out)[(((size_t)(cc * 8 + hh) * 64 + d) << 9) + j] = f2bf(val);
        }
      }
    }
}

__global__ __launch_bounds__(256, 2) void proj_gemm(
    const short* qb, const short* kb, const short* vb,
    const short* Wqt, const short* Wkt, const short* Wvt,
    const float* bq, const float* bk, const float* bvs,
    float* Qp, short* Kb, short* Vt) {
  const short* A; const short* Wt; const float* bias; void* out; int omode;
  switch (blockIdx.z) {
    case 0: A = qb; Wt = Wqt; bias = bq; out = Qp; omode = 0; break;
    case 1: A = kb; Wt = Wkt; bias = bk; out = Kb; omode = 1; break;
    default: A = vb; Wt = Wvt; bias = bvs; out = Vt; omode = 2; break;
  }
  gemm_body(A, Wt, bias, out, omode);
}

__global__ __launch_bounds__(256, 2) void out_gemm(
    const short* Hc, const short* Wot, const float* bo, float* out) {
  gemm_body(Hc, Wot, bo, out, 0);
}

// ---------------------------------------------------------------------------
// Fused attention. 1-D grid of 512 blocks with XCD-affinity swizzle:
//   h = bx & 7  -> consecutive blockIdx round-robin across the 8 XCDs, so
//   all 64 blocks of head h land on XCD h and the head's 512 KB K/V working
//   set stays resident in that XCD's 4 MB L2 (staging latency ~200 cyc
//   instead of cross-XCD/L3 ~600-900 cyc; the 32 barrier-phase drains were
//   the R5 stall).  b = (bx>>3)&3, it = bx>>5 (32 q-rows per block).
// 4 waves (wi = i-half, wj = K-split half). Per jt (8 j-tiles), 4 phases:
//   ph2=0: QK^T c=0,1 [stage K c2,c3]; ph2=1: QK^T c=2,3, R->Rs [stage V
//   c0,c1]; ph2=2: R@V c=0,1 [stage V c2,c3]; ph2=3: R@V c=2,3 [stage next K].
// All acc[] indices compile-time (R3 lesson: runtime idx => scratch spill).
// Epilogue: cross-wj reduction via xch, softmax(64) + LN, sum c, +4*qh.
// LDS: 32K stage + 4.6K Rs + 8K xch = 44.6 KB.
// ---------------------------------------------------------------------------
__global__ __launch_bounds__(256, 3) void attn2_kernel(
    const float* __restrict__ Qp, const short* __restrict__ Kb,
    const short* __restrict__ Vt, const float* __restrict__ alpha,
    const float* __restrict__ beta, short* __restrict__ Hc) {
  __shared__ __align__(16) short Stage[2][2 * 4096];  // 2 bufs x 2 tiles
  __shared__ __align__(16) short Rs[32][72];
  __shared__ __align__(16) float xch[16 * 128];

  const int bx = blockIdx.x;
  const int h = bx & 7;            // XCD-affinity: same h -> same XCD (mod-8)
  const int b = (bx >> 3) & 3;
  const int it = bx >> 5;
  const int i0 = it * 32;
  const int tid = threadIdx.x;
  const int w = tid >> 6, lane = tid & 63;
  const int l15 = lane & 15, q = lane >> 4;
  const int wi = w >> 1, wj = w & 1;
  const int wu = __builtin_amdgcn_readfirstlane(w);

  // Q A-fragments (rows i0 + wi*16 + l15), fp32 -> bf16, reused throughout.
  const float* qrow =
      Qp + (size_t)(b * SEQ + i0 + wi * 16 + l15) * DMODEL + h * DKH;
  const bf16x8 aq0 = cvt8(*(const float4*)(qrow + q * 8),
                          *(const float4*)(qrow + q * 8 + 4));
  const bf16x8 aq1 = cvt8(*(const float4*)(qrow + 32 + q * 8),
                          *(const float4*)(qrow + 32 + q * 8 + 4));

  // Staging lane constants: issue0 rows 0..31, issue1 rows 32..63; physical
  // slot lane&7 holds logical chunk (lane&7)^(row&7), row&7 = lane>>3.
  const int srow0 = wu * 8 + (lane >> 3);
  const int scol = (lane & 7) ^ (lane >> 3);

  const short* kbase_h = Kb + h * DKH;
  const short* vbase_h = Vt + (((size_t)h * DKH) << 9);

  // stage one 64x64 bf16 tile (rows at g0, row-stride rs) into buf/tslot.
#define STG1(g0, rs, buf, tslot)                                          \
  {                                                                       \
    async_cp16((g0) + (size_t)srow0 * (rs) + scol * 8,                    \
               &Stage[buf][(tslot) * 4096 + wu * 512]);                   \
    async_cp16((g0) + (size_t)(srow0 + 32) * (rs) + scol * 8,             \
               &Stage[buf][(tslot) * 4096 + (4 + wu) * 512]);             \
  }
  // K tile for batch c, j-tile j0 / V^T tile for batch c, j-tile j0
#define KTILE(c, j0) (kbase_h + ((size_t)((c) * SEQ) + (j0)) * DMODEL)
#define VTILE(c, j0) (vbase_h + (((size_t)((c) * NHEAD * DKH)) << 9) + (j0))

  f32x4 acc[4][4] = {};          // R@V partials [c][nt] — static idx only
  float sacc[2][4], ebb[2][4];

  // prologue: stage K c0,c1 of jt=0 into buf 0
  STG1(KTILE(0, 0), DMODEL, 0, 0);
  STG1(KTILE(1, 0), DMODEL, 0, 1);

  for (int jt = 0; jt < 8; ++jt) {
    const int j0 = jt * 64;
    bf16x8 ar;  // R A-fragment for this jt (loaded at ph2==2)
#pragma unroll
    for (int ph2 = 0; ph2 < 4; ++ph2) {
      __syncthreads();  // drains stage(jt,ph2); frees buf (ph2^1)
      const int buf = ph2 & 1, nbuf = buf ^ 1;
      // ---- stage next phase (overlaps this phase's compute) ----
      if (ph2 == 0) {
        STG1(KTILE(2, j0), DMODEL, nbuf, 0);
        STG1(KTILE(3, j0), DMODEL, nbuf, 1);
      } else if (ph2 == 1) {
        STG1(VTILE(0, j0), SEQ, nbuf, 0);
        STG1(VTILE(1, j0), SEQ, nbuf, 1);
      } else if (ph2 == 2) {
        STG1(VTILE(2, j0), SEQ, nbuf, 0);
        STG1(VTILE(3, j0), SEQ, nbuf, 1);
      } else if (jt < 7) {
        STG1(KTILE(0, j0 + 64), DMODEL, nbuf, 0);
        STG1(KTILE(1, j0 + 64), DMODEL, nbuf, 1);
      }
      if (ph2 < 2) {
        // ---- QK^T for c = ph2*2, ph2*2+1 (compile-time) ----
        if (ph2 == 0) {
#pragma unroll
          for (int t = 0; t < 2; ++t)
#pragma unroll
            for (int r = 0; r < 4; ++r) { sacc[t][r] = 0.0f; ebb[t][r] = 0.0f; }
        }
#pragma unroll
        for (int ct = 0; ct < 2; ++ct) {
          const int c = ph2 * 2 + ct;
          const short* S = &Stage[buf][ct * 4096];
#pragma unroll
          for (int ntl = 0; ntl < 2; ++ntl) {
            const int row = (wj * 2 + ntl) * 16 + l15;
            const int p0 = q ^ (l15 & 7);
            bf16x8 b0 = *(const bf16x8*)&S[row * 64 + p0 * 8];
            bf16x8 b1 = *(const bf16x8*)&S[row * 64 + (p0 ^ 4) * 8];
            f32x4 s = {};
            s = __builtin_amdgcn_mfma_f32_16x16x32_bf16(aq0, b0, s, 0, 0, 0);
            s = __builtin_amdgcn_mfma_f32_16x16x32_bf16(aq1, b1, s, 0, 0, 0);
#pragma unroll
            for (int r = 0; r < 4; ++r) {
              const float e = __expf(s[r]);
              sacc[ntl][r] += e;
              ebb[ntl][r] = (c == b) ? e : ebb[ntl][r];
            }
          }
        }
        if (ph2 == 1) {  // fenmu complete -> R tile (bf16)
#pragma unroll
          for (int ntl = 0; ntl < 2; ++ntl)
#pragma unroll
            for (int r = 0; r < 4; ++r)
              Rs[wi * 16 + q * 4 + r][(wj * 2 + ntl) * 16 + l15] =
                  f2bf(ebb[ntl][r] / (8.0f * sacc[ntl][r]));
        }
      } else {
        // ---- R@V partial for c = (ph2-2)*2 + ct (compile-time) ----
        if (ph2 == 2) ar = *(const bf16x8*)&Rs[wi * 16 + l15][wj * 32 + q * 8];
#pragma unroll
        for (int ct = 0; ct < 2; ++ct) {
          const int c = (ph2 - 2) * 2 + ct;
          const short* S = &Stage[buf][ct * 4096];
#pragma unroll
          for (int nt = 0; nt < 4; ++nt) {
            const int row = nt * 16 + l15;
            const int pb = (wj * 4 + q) ^ (l15 & 7);
            bf16x8 bv = *(const bf16x8*)&S[row * 64 + pb * 8];
            acc[c][nt] = __builtin_amdgcn_mfma_f32_16x16x32_bf16(
                ar, bv, acc[c][nt], 0, 0, 0);
          }
        }
      }
    }
  }
#undef STG1
#undef KTILE
#undef VTILE

  // ---- cross-wj score reduction (K-halves) into wj==0 waves ----
#pragma unroll
  for (int c = 0; c < BSZ; ++c) {
    if (wj == 1) {
#pragma unroll
      for (int nt = 0; nt < 4; ++nt)
#pragma unroll
        for (int r = 0; r < 4; ++r)
          xch[(nt * 4 + r) * 128 + wi * 64 + lane] = acc[c][nt][r];
    }
    __syncthreads();
    if (wj == 0) {
#pragma unroll
      for (int nt = 0; nt < 4; ++nt)
#pragma unroll
        for (int r = 0; r < 4; ++r)
          acc[c][nt][r] += xch[(nt * 4 + r) * 128 + wi * 64 + lane];
    }
    __syncthreads();
  }

  if (wj == 0) {
    float al[4], be[4];
#pragma unroll
    for (int nt = 0; nt < 4; ++nt) {
      al[nt] = alpha[nt * 16 + l15];
      be[nt] = beta[nt * 16 + l15];
    }
    float hacc[4][4] = {};  // [r][nt]
#pragma unroll
    for (int c = 0; c < BSZ; ++c) {
#pragma unroll
      for (int r = 0; r < 4; ++r) {
        float e0 = __expf(acc[c][0][r]), e1 = __expf(acc[c][1][r]);
        float e2 = __expf(acc[c][2][r]), e3 = __expf(acc[c][3][r]);
        float es = e0 + e1 + e2 + e3;
#pragma unroll
        for (int m = 8; m >= 1; m >>= 1) es += __shfl_xor(es, m);
        const float inv = 1.0f / es;
        const float d0 = e0 * inv - 0.015625f, d1 = e1 * inv - 0.015625f;
        const float d2 = e2 * inv - 0.015625f, d3 = e3 * inv - 0.015625f;
        float sq = d0 * d0 + d1 * d1 + d2 * d2 + d3 * d3;
#pragma unroll
        for (int m = 8; m >= 1; m >>= 1) sq += __shfl_xor(sq, m);
        const float rs = 1.0f / (sqrtf(sq * (1.0f / 63.0f)) + EPSLN);
        hacc[r][0] += al[0] * d0 * rs + be[0];
        hacc[r][1] += al[1] * d1 * rs + be[1];
        hacc[r][2] += al[2] * d2 * rs + be[2];
        hacc[r][3] += al[3] * d3 * rs + be[3];
      }
    }
#pragma unroll
    for (int r = 0; r < 4; ++r) {
      const size_t rowoff =
          (size_t)(b * SEQ + i0 + wi * 16 + q * 4 + r) * DMODEL + h * DKH;
#pragma unroll
      for (int nt = 0; nt < 4; ++nt) {
        const int d = nt * 16 + l15;
        const float o = hacc[r][nt] + 4.0f * Qp[rowoff + d];
        Hc[rowoff + d] = f2bf(o);
      }
    }
  }
}

// ---------------------------------------------------------------------------
extern "C" void kernel_launch(void* const* d_in, const int* in_sizes, int n_in,
                              void* d_out, int out_size, void* d_ws,
                              size_t ws_size, hipStream_t stream) {
  (void)in_sizes; (void)n_in; (void)out_size; (void)ws_size;
  const float* q = (const float*)d_in[0];
  const float* k = (const float*)d_in[1];
  const float* v = (const float*)d_in[2];
  const float* Wq = (const float*)d_in[3];
  const float* bq = (const float*)d_in[4];
  const float* Wk = (const float*)d_in[5];
  const float* bk = (const float*)d_in[6];
  const float* Wv = (const float*)d_in[7];
  const float* bv = (const float*)d_in[8];
  const float* Wo = (const float*)d_in[9];
  const float* bo = (const float*)d_in[10];
  const float* alpha = (const float*)d_in[11];
  const float* beta = (const float*)d_in[12];
  float* out = (float*)d_out;

  char* wsb = (char*)d_ws;
  short* qb = (short*)(wsb);
  short* kb = (short*)(wsb + (2u << 20));
  short* vb = (short*)(wsb + (4u << 20));
  float* Qp = (float*)(wsb + (6u << 20));
  short* Kb = (short*)(wsb + (10u << 20));
  short* Vtg = (short*)(wsb + (12u << 20));
  short* Hc = (short*)(wsb + (14u << 20));
  short* Wqt = (short*)(wsb + (16u << 20));
  short* Wkt = (short*)(wsb + (16u << 20) + (512u << 10));
  short* Wvt = (short*)(wsb + (17u << 20));
  short* Wot = (short*)(wsb + (17u << 20) + (512u << 10));

  prep_kernel<<<dim3(1792), 256, 0, stream>>>(q, k, v, qb, kb, vb,
                                              Wq, Wk, Wv, Wo,
                                              Wqt, Wkt, Wvt, Wot);
  proj_gemm<<<dim3(4, 16, 3), 256, 0, stream>>>(qb, kb, vb, Wqt, Wkt, Wvt,
                                                bq, bk, bv, Qp, Kb, Vtg);
  attn2_kernel<<<dim3(512), 256, 0, stream>>>(Qp, Kb, Vtg, alpha, beta, Hc);
  out_gemm<<<dim3(4, 16), 256, 0, stream>>>(Hc, Wot, bo, out);
}